// Round 10
// baseline (177.643 us; speedup 1.0000x reference)
//
#include <hip/hip_runtime.h>

#define GH 64
#define LS 32
#define HF 32
#define DS 16

// transcendental folding constants (exact fp32 rescale of weights at prep)
#define NLOG2E -1.4426950408889634f   // r,z columns:  sigm(x)=rcp(1+exp2(-log2e*x))
#define P2LOG2E 2.8853900817779268f   // n columns:    tanh(x)=1-2*rcp(exp2(2log2e*x)+1)

typedef short bf16x8 __attribute__((ext_vector_type(8)));
typedef float f32x4 __attribute__((ext_vector_type(4)));

#define MFMA16(a, b, c) __builtin_amdgcn_mfma_f32_16x16x32_bf16(a, b, c, 0, 0, 0)

__device__ __forceinline__ unsigned int f2bf_rne(float f) {
    unsigned int u = __float_as_uint(f);
    return (u + 0x7FFFu + ((u >> 16) & 1u)) >> 16;   // RNE (prep kernel only)
}
__device__ __forceinline__ unsigned short f2bf_h(float f) {
    return (unsigned short)((__float_as_uint(f) + 0x8000u) >> 16);  // half-up
}
__device__ __forceinline__ unsigned int pack_trunc(float v0, float v1) {
    return __builtin_amdgcn_perm(__float_as_uint(v1), __float_as_uint(v0),
                                 0x07060302u);   // (bf16(v1)<<16)|bf16(v0)
}
__device__ __forceinline__ bf16x8 as_frag(uint4 u) {
    union { uint4 a; bf16x8 b; } cv; cv.a = u; return cv.b;
}

// A-fragment from one 16x64 bf16 slot, XOR-swizzled 16B blocks:
// (seq,ch) at seq*64 + (((ch>>3)^(seq&7))<<3) + (ch&7). Conflict-free b128.
__device__ __forceinline__ bf16x8 ld_afrag(const unsigned short* slot, int m,
                                           int quad, int half) {
    int b   = half * 4 + quad;
    int idx = (m << 6) + ((b ^ (m & 7)) << 3);
    return as_frag(*reinterpret_cast<const uint4*>(slot + idx));
}

// Layer-0 input A-frag on the fly: relu(xv*siW[ch]+sib[ch]) for 8 channels.
__device__ __forceinline__ bf16x8 build_l0(float xv, const float* w, const float* b) {
    float4 w0 = reinterpret_cast<const float4*>(w)[0];
    float4 w1 = reinterpret_cast<const float4*>(w)[1];
    float4 b0 = reinterpret_cast<const float4*>(b)[0];
    float4 b1 = reinterpret_cast<const float4*>(b)[1];
    float v0 = fmaxf(fmaf(xv, w0.x, b0.x), 0.0f);
    float v1 = fmaxf(fmaf(xv, w0.y, b0.y), 0.0f);
    float v2 = fmaxf(fmaf(xv, w0.z, b0.z), 0.0f);
    float v3 = fmaxf(fmaf(xv, w0.w, b0.w), 0.0f);
    float v4 = fmaxf(fmaf(xv, w1.x, b1.x), 0.0f);
    float v5 = fmaxf(fmaf(xv, w1.y, b1.y), 0.0f);
    float v6 = fmaxf(fmaf(xv, w1.z, b1.z), 0.0f);
    float v7 = fmaxf(fmaf(xv, w1.w, b1.w), 0.0f);
    union { uint4 u; bf16x8 v; } cv;
    cv.u.x = pack_trunc(v0, v1);
    cv.u.y = pack_trunc(v2, v3);
    cv.u.z = pack_trunc(v4, v5);
    cv.u.w = pack_trunc(v6, v7);
    return cv.v;
}

// ---- prep: fp32 weights -> bf16 MFMA B-fragments, fragment-ordered, with
// transcendental scales FOLDED IN. idx = rest*1024 + kc*512 + lane*8 + j.
// GRU (rest<96): rest=(l*6+mat)*4+jt, mat 0..2 = Wih r/z/n, 3..5 = Whh r/z/n.
// Epi (rest=96..103): rest=96+m2*4+jt, m2: 0=soW (unscaled), 1=s2sW.
__global__ __launch_bounds__(256) void prep_weights(
    const float* __restrict__ Wih, const float* __restrict__ Whh,
    const float* __restrict__ soW, const float* __restrict__ s2sW,
    unsigned short* __restrict__ wsW)
{
    int idx = blockIdx.x * 256 + threadIdx.x;
    if (idx >= 104 * 1024) return;
    int j = idx & 7, lane = (idx >> 3) & 63, kc = (idx >> 9) & 1, rest = idx >> 10;
    int k = kc * 32 + ((lane >> 4) << 3) + j;
    int c = lane & 15;
    float v;
    if (rest < 96) {
        int jt = rest & 3, mt = rest >> 2;
        int l = mt / 6, mat = mt - l * 6;
        int col = jt * 16 + c;
        const float* W = (mat < 3) ? Wih + (size_t)l * GH * 192
                                   : Whh + (size_t)l * GH * 192;
        int m3 = (mat < 3) ? mat : mat - 3;
        v = W[k * 192 + m3 * 64 + col];
        v *= (m3 == 2) ? P2LOG2E : NLOG2E;       // fold trans scale
    } else {
        int r2 = rest - 96;
        int jt = r2 & 3, m2 = r2 >> 2;
        int col = jt * 16 + c;
        v = (m2 ? s2sW : soW)[k * 64 + col];
        if (m2 && jt < 2) v *= NLOG2E;           // A_s sigmoid half
    }
    wsW[idx] = (unsigned short)f2bf_rne(v);
}

// 1024 threads = 16 waves = (layer l = wid>>2) x (col-tile jt = wid&3) so each
// SIMD (= wid&3) hosts one wave of every layer. Block owns 2 groups x 16 seqs.
// Layer-pipelined GRU: at step tau, layer l does t = tau-l; activations flow
// through 2-slot rings (ring: relu'd, layer l -> l+1; hrec: pre-relu, own-layer
// recurrence). ONE barrier per step, 35 steps. B-fragments loaded ONCE per
// kernel from prepped ws. Fused slow_out/s2s epilogue + fast SSM, one dispatch.
__global__ __launch_bounds__(1024, 4) void slowfast_fused(
    const float* __restrict__ x,
    const float* __restrict__ siW,  const float* __restrict__ sib,
    const float* __restrict__ bih,  const float* __restrict__ bhh,
    const float* __restrict__ sob,  const float* __restrict__ s2sb,
    const float* __restrict__ finW, const float* __restrict__ finb,
    const float* __restrict__ foutW, const float* __restrict__ foutb,
    const unsigned short* __restrict__ wsW,
    float* __restrict__ out,
    int T, int ns, int BS)
{
    __shared__ __align__(16) unsigned short ring[2][3][2][1024];  // 24 KB relu'd
    __shared__ __align__(16) unsigned short hrec[2][4][2][1024];  // 32 KB pre-relu
    __shared__ __align__(16) unsigned short h31[2][1024];         // 4 KB h3[31]
    __shared__ float xs[2][16 * 33];    // x windows (pad-33)
    __shared__ float AG[2][16 * 65];    // A_s | g_s staging (pad-65)
    __shared__ float swb[128];          // siW[64] | sib[64]

    const int tid  = threadIdx.x;
    const int lane = tid & 63;
    const int wid  = tid >> 6;
    const int l    = wid >> 2;          // layer
    const int jt   = wid & 3;           // col tile
    const int c    = lane & 15;
    const int quad = lane >> 4;
    const int col  = jt * 16 + c;
    const int seqbase = blockIdx.x * 32;
    const uint4* wf = reinterpret_cast<const uint4*>(wsW);

    // ---- stage x windows (32 seq-slots x 32 t = 1024, one pass) ----
    {
        int s32 = tid >> 5, t = tid & 31;
        int q = seqbase + s32; if (q > BS - 1) q = BS - 1;
        int b  = (q >= ns) ? 1 : 0;
        int si = q - b * ns;
        xs[s32 >> 4][(s32 & 15) * 33 + t] = x[b * T + si * DS + t];
    }
    if (tid < 64) { swb[tid] = siW[tid]; swb[64 + tid] = sib[tid]; }

    // ---- B-fragments for (l, jt): loaded ONCE (12 coalesced dwordx4) ----
    bf16x8 BiR[2], BiZ[2], BiN[2], BhR[2], BhZ[2], BhN[2];
    #pragma unroll
    for (int kc = 0; kc < 2; ++kc) {
        int base = (l * 6 * 4 + jt) * 128 + kc * 64 + lane;   // mat stride 512
        BiR[kc] = as_frag(wf[base]);
        BiZ[kc] = as_frag(wf[base + 512]);
        BiN[kc] = as_frag(wf[base + 1024]);
        BhR[kc] = as_frag(wf[base + 1536]);
        BhZ[kc] = as_frag(wf[base + 2048]);
        BhN[kc] = as_frag(wf[base + 2560]);
    }
    // biases with folded scales (r,z merged ih+hh; n kept separate)
    float bRs  = NLOG2E  * (bih[l * 192 + col]      + bhh[l * 192 + col]);
    float bZs  = NLOG2E  * (bih[l * 192 + 64 + col] + bhh[l * 192 + 64 + col]);
    float bNIs = P2LOG2E * bih[l * 192 + 128 + col];
    float bNHs = P2LOG2E * bhh[l * 192 + 128 + col];   // tanh(xg_n + r*hg_n)
    const f32x4 vbR  = (f32x4){bRs,  bRs,  bRs,  bRs};
    const f32x4 vbZ  = (f32x4){bZs,  bZs,  bZs,  bZs};
    const f32x4 vbNI = (f32x4){bNIs, bNIs, bNIs, bNIs};
    const f32x4 vbNH = (f32x4){bNHs, bNHs, bNHs, bNHs};

    int wIdx[4];    // hoisted swizzled indices for this lane's 4 gate elements
    #pragma unroll
    for (int i = 0; i < 4; ++i) {
        int row = quad * 4 + i;
        wIdx[i] = (row << 6) + ((((col >> 3) ^ (row & 7))) << 3) + (col & 7);
    }

    float hprev[2][4] = {{0, 0, 0, 0}, {0, 0, 0, 0}};

    __syncthreads();

    // ---- pipelined main loop: one barrier per step ----
    #pragma unroll 2
    for (int tau = 0; tau < LS + 3; ++tau) {
        int t = tau - l;
        if (t >= 0 && t < LS) {
            #pragma unroll
            for (int grp = 0; grp < 2; ++grp) {
                bf16x8 a0, a1;
                if (l == 0) {
                    float xv = xs[grp][c * 33 + t];
                    a0 = build_l0(xv, &swb[quad * 8],      &swb[64 + quad * 8]);
                    a1 = build_l0(xv, &swb[32 + quad * 8], &swb[96 + quad * 8]);
                } else {
                    const unsigned short* ab = ring[grp][l - 1][t & 1];
                    a0 = ld_afrag(ab, c, quad, 0);       // relu'd prev-layer h
                    a1 = ld_afrag(ab, c, quad, 1);
                }
                f32x4 aR  = MFMA16(a0, BiR[0], vbR);
                f32x4 aZ  = MFMA16(a0, BiZ[0], vbZ);
                f32x4 aNI = MFMA16(a0, BiN[0], vbNI);
                aR  = MFMA16(a1, BiR[1], aR);
                aZ  = MFMA16(a1, BiZ[1], aZ);
                aNI = MFMA16(a1, BiN[1], aNI);
                f32x4 aNH = vbNH;
                if (t > 0) {
                    const unsigned short* hb = hrec[grp][l][(t - 1) & 1];
                    bf16x8 h0 = ld_afrag(hb, c, quad, 0);   // pre-relu recurrent
                    bf16x8 h1 = ld_afrag(hb, c, quad, 1);
                    aR  = MFMA16(h0, BhR[0], aR);
                    aZ  = MFMA16(h0, BhZ[0], aZ);
                    aNH = MFMA16(h0, BhN[0], aNH);
                    aR  = MFMA16(h1, BhR[1], aR);
                    aZ  = MFMA16(h1, BhZ[1], aZ);
                    aNH = MFMA16(h1, BhN[1], aNH);
                }
                unsigned short* wr = hrec[grp][l][t & 1];
                unsigned short* wb = (l < 3) ? ring[grp][l][t & 1] : h31[grp];
                bool wrelu = (l < 3) | (t == LS - 1);
                #pragma unroll
                for (int i = 0; i < 4; ++i) {
                    // scales folded into weights: exp2 directly on accumulators
                    float r  = __builtin_amdgcn_rcpf(1.0f + __builtin_amdgcn_exp2f(aR[i]));
                    float z  = __builtin_amdgcn_rcpf(1.0f + __builtin_amdgcn_exp2f(aZ[i]));
                    float e  = __builtin_amdgcn_exp2f(fmaf(r, aNH[i], aNI[i]));
                    float n  = fmaf(-2.0f, __builtin_amdgcn_rcpf(e + 1.0f), 1.0f);
                    float hn = fmaf(z, hprev[grp][i] - n, n);
                    hprev[grp][i] = hn;
                    wr[wIdx[i]] = f2bf_h(hn);                       // pre-relu
                    if (wrelu)
                        wb[wIdx[i]] = f2bf_h(fmaxf(hn, 0.0f));      // relu'd
                }
            }
        }
        __syncthreads();   // slot written at tau is read at tau+1
    }

    // ---- fused epilogue ----
    // E1 (waves 0-7): slow_feat = h31 @ soW + sob -> stage bf16 in ring[g][0][0]
    if (wid < 8) {
        int grp1 = l;                                  // wid>>2 in {0,1}
        bf16x8 e0 = ld_afrag(h31[grp1], c, quad, 0);
        bf16x8 e1 = ld_afrag(h31[grp1], c, quad, 1);
        bf16x8 Bso[2];
        #pragma unroll
        for (int kc = 0; kc < 2; ++kc)
            Bso[kc] = as_frag(wf[(96 + jt) * 128 + kc * 64 + lane]);
        float sb = sob[col];
        f32x4 accS = (f32x4){sb, sb, sb, sb};
        accS = MFMA16(e0, Bso[0], accS);
        accS = MFMA16(e1, Bso[1], accS);
        unsigned short* sf = ring[grp1][0][0];         // dead slot
        #pragma unroll
        for (int i = 0; i < 4; ++i)
            sf[wIdx[i]] = f2bf_h(accS[i]);
    }
    __syncthreads();
    // E2 (waves 8-15): eps = sf @ s2sW + s2sb -> A_s | g_s
    if (wid >= 8) {
        int grp2 = l - 2;
        bf16x8 s0 = ld_afrag(ring[grp2][0][0], c, quad, 0);
        bf16x8 s1 = ld_afrag(ring[grp2][0][0], c, quad, 1);
        bf16x8 Bs2[2];
        #pragma unroll
        for (int kc = 0; kc < 2; ++kc)
            Bs2[kc] = as_frag(wf[(100 + jt) * 128 + kc * 64 + lane]);
        float eb = (jt < 2) ? NLOG2E * s2sb[col] : s2sb[col];
        f32x4 accE = (f32x4){eb, eb, eb, eb};
        accE = MFMA16(s0, Bs2[0], accE);
        accE = MFMA16(s1, Bs2[1], accE);
        #pragma unroll
        for (int i = 0; i < 4; ++i) {
            int row = quad * 4 + i;
            float v = accE[i];
            AG[grp2][row * 65 + col] = (jt < 2)
                ? __builtin_amdgcn_rcpf(1.0f + __builtin_amdgcn_exp2f(v)) : v;
        }
    }
    __syncthreads();
    // E3: fast diagonal SSM + overlap-add (32 frames x 32 ch, one pass)
    {
        int frame = tid >> 5, fch = tid & 31;
        int grpf = frame >> 4, fr = frame & 15;
        int q = seqbase + frame;
        if (q < BS) {            // skip duplicated clamp frames (no double-add)
            int b  = (q >= ns) ? 1 : 0;
            int fi = q - b * ns;
            float cA = AG[grpf][fr * 65 + fch];
            float cG = AG[grpf][fr * 65 + 32 + fch];
            float Gf = finW[fch] * cG;
            float Gb = finb[fch] * cG;
            float cFo = foutW[fch];
            float cfb = foutb[0];
            float h = 0.0f;
            const float* xrow = xs[grpf] + fr * 33;
            float* op = out + (size_t)b * T + fi * DS;
            #pragma unroll 1
            for (int t = 0; t < LS; ++t) {
                h = fmaf(cA, h, fmaf(xrow[t], Gf, Gb));
                float s = h * cFo;
                s += __shfl_xor(s, 1);
                s += __shfl_xor(s, 2);
                s += __shfl_xor(s, 4);
                s += __shfl_xor(s, 8);
                s += __shfl_xor(s, 16);
                if (fch == 0) atomicAdd(&op[t], s + cfb);
            }
        }
    }
}

extern "C" void kernel_launch(void* const* d_in, const int* in_sizes, int n_in,
                              void* d_out, int out_size, void* d_ws, size_t ws_size,
                              hipStream_t stream)
{
    (void)n_in; (void)ws_size;
    const float* x     = (const float*)d_in[0];
    const float* siW   = (const float*)d_in[1];
    const float* sib   = (const float*)d_in[2];
    const float* Wih   = (const float*)d_in[3];
    const float* Whh   = (const float*)d_in[4];
    const float* bih   = (const float*)d_in[5];
    const float* bhh   = (const float*)d_in[6];
    const float* soW   = (const float*)d_in[7];
    const float* sob   = (const float*)d_in[8];
    const float* s2sW  = (const float*)d_in[9];
    const float* s2sb  = (const float*)d_in[10];
    const float* finW  = (const float*)d_in[11];
    const float* finb  = (const float*)d_in[12];
    const float* foutW = (const float*)d_in[13];
    const float* foutb = (const float*)d_in[14];

    int T  = in_sizes[0] / 2;          // B = 2
    int ns = (T - LS) / DS + 1;        // 3999
    int BS = 2 * ns;                   // 7998

    unsigned short* wsW = (unsigned short*)d_ws;   // 104*1024 bf16 = 208 KB

    (void)hipMemsetAsync(d_out, 0, (size_t)out_size * sizeof(float), stream);

    prep_weights<<<dim3(416), dim3(256), 0, stream>>>(Wih, Whh, soW, s2sW, wsW);

    slowfast_fused<<<dim3((BS + 31) / 32), dim3(1024), 0, stream>>>(
        x, siW, sib, bih, bhh, sob, s2sb, finW, finb, foutW, foutb,
        wsW, (float*)d_out, T, ns, BS);
}